// Round 1
// baseline (502.286 us; speedup 1.0000x reference)
//
#include <hip/hip_runtime.h>
#include <math.h>

// Problem constants (from reference)
#define NB 32
#define NH 32
#define NKV 8
#define NG 4          // H / HKV
#define DH 128
#define MAXL 2048
#define CHUNK 32
#define NCH (MAXL / CHUNK)   // 64
#define ROWF (NKV * DH)      // floats between consecutive cache positions (1024)

// (1/sqrt(128)) * log2(e) so scores live in log2 domain (native v_exp_f32)
#define SCALE_LOG2E 0.12752966529379885f

// Single-instruction cross-lane adds via DPP (identity 0 for out-of-row lanes).
template <int CTRL>
__device__ __forceinline__ float dpp_add(float x) {
    int y = __builtin_amdgcn_update_dpp(0, __float_as_int(x), CTRL, 0xf, 0xf, false);
    return x + __int_as_float(y);
}
// After this, lane31 = sum(lanes 0..31), lane63 = sum(lanes 32..63).
__device__ __forceinline__ float half_reduce_sum(float d) {
    d = dpp_add<0x111>(d);   // row_shr:1
    d = dpp_add<0x112>(d);   // row_shr:2
    d = dpp_add<0x114>(d);   // row_shr:4
    d = dpp_add<0x118>(d);   // row_shr:8
    d = dpp_add<0x142>(d);   // row_bcast:15
    return d;
}

// Kernel 1: per-(batch, 32-pos chunk) partial attention over ALL 8 kv heads.
// Block = 256 threads = 8 half-waves; half-wave hw owns kv-head hw.
// Per position the block loads ONE fully-contiguous 4 KB cache row
// (thread tid reads floats [4*tid, 4*tid+4)), so K/V streaming is perfectly
// sequential — no 512B-per-4KB strided pattern. Each half-wave sees every
// position of the chunk, so its PV accumulator is complete: no cross-half
// LDS reduction (sacc) needed at all.
__global__ __launch_bounds__(256) void attn_partial_kernel(
    const float* __restrict__ q,
    const float* __restrict__ knew,
    const float* __restrict__ vnew,
    const float* __restrict__ kcache,
    const float* __restrict__ vcache,
    const int* __restrict__ base_offsets,
    const int* __restrict__ live_counts,
    const int* __restrict__ slot_mapping,
    float* __restrict__ pml,    // [NB*NKV*NG*NCH][2]  (m, l)
    float* __restrict__ pacc)   // [NB*NKV*NG*NCH][DH] unnormalized acc
{
    const int c = blockIdx.x;   // chunk
    const int b = blockIdx.y;   // batch

    const int live = live_counts[b];
    const int p0 = c * CHUNK;
    if (p0 >= live) return;     // block-uniform early exit

    const int base = base_offsets[b];
    const int rep  = slot_mapping[b] - base;   // position replaced by knew/vnew

    const int tid  = (int)threadIdx.x;
    const int lane = tid & 63;
    const int ql   = lane & 31;
    const int hw   = tid >> 5;   // half-wave id == kv head owned

    __shared__ float sc[NKV][NG][CHUNK];   // scores, then p-weights (4 KB)

    // Q fragments for this head's 4 grouped query heads
    float4 qv[NG];
#pragma unroll
    for (int g = 0; g < NG; ++g)
        qv[g] = *(const float4*)(q + (size_t)(b * NH + hw * NG + g) * DH + ql * 4);

    const float4 kn4 = *(const float4*)(knew + (size_t)(b * NKV + hw) * DH + ql * 4);
    const float4 vn4 = *(const float4*)(vnew + (size_t)(b * NKV + hw) * DH + ql * 4);

    const int lim = live - 1;
    // This thread's slice of every cache row: head hw, dims [ql*4, ql*4+4)
    // == floats [tid*4, tid*4+4) of the 1024-float row. Contiguous per block.
    const float* kb = kcache + (size_t)base * ROWF + tid * 4;
    const float* vb = vcache + (size_t)base * ROWF + tid * 4;

    // ---- Phase 1: scores (streams K, one 4 KB row per iteration).
    // Branch-free: clamped addresses, dead positions get -inf.
#pragma unroll 8
    for (int i = 0; i < CHUNK; ++i) {
        const int p  = p0 + i;
        const int pc = min(p, lim);
        float4 kk = *(const float4*)(kb + ((size_t)pc << 10));
        if (pc == rep) kk = kn4;          // virtual scatter of the new token
#pragma unroll
        for (int g = 0; g < NG; ++g) {
            float d = kk.x * qv[g].x + kk.y * qv[g].y +
                      kk.z * qv[g].z + kk.w * qv[g].w;
            d = half_reduce_sum(d);
            const float s = (p <= lim) ? d * SCALE_LOG2E : -INFINITY;
            if (ql == 31) sc[hw][g][i] = s;   // lanes 31 & 63 write their head
        }
    }
    __syncthreads();   // intra-wave sharing only; barrier is safety

    // ---- Phase 2: softmax over the chunk; half-wave hw owns head hw.
#pragma unroll
    for (int g = 0; g < NG; ++g) {
        const float s = sc[hw][g][ql];
        float m = s;
#pragma unroll
        for (int off = 1; off < 32; off <<= 1)
            m = fmaxf(m, __shfl_xor(m, off));   // stays within the half-wave
        const float e = exp2f(s - m);
        float l = e;
#pragma unroll
        for (int off = 1; off < 32; off <<= 1)
            l += __shfl_xor(l, off);
        sc[hw][g][ql] = e;                      // weights back to LDS
        if (ql == 0) {
            const size_t pidx = ((size_t)(b * NKV + hw) * NG + g) * NCH + c;
            pml[pidx * 2]     = m;
            pml[pidx * 2 + 1] = l;
        }
    }
    __syncthreads();

    // ---- Phase 3: PV (streams V, one 4 KB row per iteration).
    float4 acc[NG];
#pragma unroll
    for (int g = 0; g < NG; ++g) acc[g] = make_float4(0.f, 0.f, 0.f, 0.f);

#pragma unroll 8
    for (int i = 0; i < CHUNK; ++i) {
        const int p  = p0 + i;
        const int pc = min(p, lim);
        float4 vv = *(const float4*)(vb + ((size_t)pc << 10));
        if (pc == rep) vv = vn4;
#pragma unroll
        for (int g = 0; g < NG; ++g) {
            const float w = sc[hw][g][i];   // broadcast read; 0 for dead pos
            acc[g].x += w * vv.x;
            acc[g].y += w * vv.y;
            acc[g].z += w * vv.z;
            acc[g].w += w * vv.w;
        }
    }

    // Accumulators are complete per half-wave — write partials directly.
#pragma unroll
    for (int g = 0; g < NG; ++g) {
        const size_t pidx = ((size_t)(b * NKV + hw) * NG + g) * NCH + c;
        *(float4*)(pacc + pidx * DH + ql * 4) = acc[g];
    }
}

// Kernel 2: LSE-combine the <=64 chunk partials per (b, kv-head, group).
// No local arrays (avoids scratch); pml re-reads are L2-hot (512 KB total).
__global__ __launch_bounds__(256) void attn_combine_kernel(
    const int* __restrict__ live_counts,
    const float* __restrict__ pml,
    const float* __restrict__ pacc,
    float* __restrict__ out)
{
    const int h = blockIdx.x;
    const int b = blockIdx.y;
    const int g = (int)threadIdx.x >> 6;
    const int lane = (int)threadIdx.x & 63;   // 64 lanes x float2 = 128 dims

    const int live = live_counts[b];
    const int nc = (live + CHUNK - 1) / CHUNK;
    const size_t pbase = ((size_t)(b * NKV + h) * NG + g) * NCH;

    float M = -INFINITY;
    for (int cj = 0; cj < nc; ++cj)
        M = fmaxf(M, pml[(pbase + cj) * 2]);
    float L = 0.f;
    for (int cj = 0; cj < nc; ++cj)
        L += exp2f(pml[(pbase + cj) * 2] - M) * pml[(pbase + cj) * 2 + 1];
    float2 o = make_float2(0.f, 0.f);
    for (int cj = 0; cj < nc; ++cj) {
        const float w = exp2f(pml[(pbase + cj) * 2] - M);
        const float2 a = *(const float2*)(pacc + (pbase + cj) * DH + lane * 2);
        o.x += w * a.x;
        o.y += w * a.y;
    }
    const float inv = 1.f / L;
    o.x *= inv; o.y *= inv;
    *(float2*)(out + (size_t)(b * NH + h * NG + g) * DH + lane * 2) = o;
}

extern "C" void kernel_launch(void* const* d_in, const int* in_sizes, int n_in,
                              void* d_out, int out_size, void* d_ws, size_t ws_size,
                              hipStream_t stream) {
    const float* q    = (const float*)d_in[0];
    const float* knew = (const float*)d_in[1];
    const float* vnew = (const float*)d_in[2];
    const float* kc   = (const float*)d_in[3];
    const float* vc   = (const float*)d_in[4];
    const int* base   = (const int*)d_in[5];
    const int* live   = (const int*)d_in[6];
    const int* slot   = (const int*)d_in[7];
    float* out = (float*)d_out;

    // Workspace: pml = 2*(32*8*4*64) floats (512 KB), pacc = 65536*128 floats (33.5 MB)
    float* pml  = (float*)d_ws;
    float* pacc = pml + (size_t)2 * NB * NKV * NG * NCH;

    dim3 grid1(NCH, NB);        // 2048 blocks, ~1040 active
    attn_partial_kernel<<<grid1, 256, 0, stream>>>(q, knew, vnew, kc, vc,
                                                   base, live, slot, pml, pacc);
    dim3 grid2(NKV, NB);        // 256 blocks
    attn_combine_kernel<<<grid2, 256, 0, stream>>>(live, pml, pacc, out);
}

// Round 2
// 496.869 us; speedup vs baseline: 1.0109x; 1.0109x over previous
//
#include <hip/hip_runtime.h>
#include <math.h>

// Problem constants (from reference)
#define NB 32
#define NH 32
#define NKV 8
#define NG 4          // H / HKV
#define DH 128
#define MAXL 2048
#define CHUNK 256
#define NCH (MAXL / CHUNK)   // 8
#define ROWF (NKV * DH)      // floats between consecutive cache positions (1024)

// (1/sqrt(128)) * log2(e) so scores live in log2 domain (native v_exp_f32)
#define SCALE_LOG2E 0.12752966529379885f

// Single-instruction cross-lane adds via DPP (identity 0 for out-of-row lanes).
template <int CTRL>
__device__ __forceinline__ float dpp_add(float x) {
    int y = __builtin_amdgcn_update_dpp(0, __float_as_int(x), CTRL, 0xf, 0xf, false);
    return x + __int_as_float(y);
}
// After this, lane31 = sum(lanes 0..31), lane63 = sum(lanes 32..63).
__device__ __forceinline__ float half_reduce_sum(float d) {
    d = dpp_add<0x111>(d);   // row_shr:1
    d = dpp_add<0x112>(d);   // row_shr:2
    d = dpp_add<0x114>(d);   // row_shr:4
    d = dpp_add<0x118>(d);   // row_shr:8
    d = dpp_add<0x142>(d);   // row_bcast:15
    return d;
}

// Kernel 1: per-(batch, kv-head, 256-pos chunk) partial attention.
// Block = 256 threads = 4 waves; wave w owns positions [c*256+64w, +64).
// Lanes 0-31 / 32-63 handle one position each per iteration:
// 32 lanes x float4 = one 512B KV row slice.
// CHUNK=256 minimizes partial-result traffic (pacc 4 MB, pml 64 KB) —
// the r1 experiment showed access pattern is cache-served and irrelevant;
// only total bytes matter.
__global__ __launch_bounds__(256) void attn_partial_kernel(
    const float* __restrict__ q,
    const float* __restrict__ knew,
    const float* __restrict__ vnew,
    const float* __restrict__ kcache,
    const float* __restrict__ vcache,
    const int* __restrict__ base_offsets,
    const int* __restrict__ live_counts,
    const int* __restrict__ slot_mapping,
    float* __restrict__ pml,    // [NB*NKV*NG*NCH][2]  (m, l)
    float* __restrict__ pacc)   // [NB*NKV*NG*NCH][DH] unnormalized acc
{
    const int c = blockIdx.x;   // chunk
    const int h = blockIdx.y;   // kv head
    const int b = blockIdx.z;   // batch

    const int live = live_counts[b];
    const int p0 = c * CHUNK;
    if (p0 >= live) return;     // block-uniform early exit

    const int base = base_offsets[b];
    const int rep  = slot_mapping[b] - base;   // position replaced by knew/vnew

    const int tid  = (int)threadIdx.x;
    const int wave = tid >> 6;
    const int lane = tid & 63;
    const int half = lane >> 5;
    const int ql   = lane & 31;

    __shared__ float  sc[NG][CHUNK];      // scores, then p-weights (4 KB)
    __shared__ float4 sacc[NG][8][32];    // half-wave PV partials (16 KB)

    // Q fragments for the 4 grouped query heads
    float4 qv[NG];
#pragma unroll
    for (int g = 0; g < NG; ++g)
        qv[g] = *(const float4*)(q + (size_t)(b * NH + h * NG + g) * DH + ql * 4);

    const float4 kn4 = *(const float4*)(knew + (size_t)(b * NKV + h) * DH + ql * 4);
    const float4 vn4 = *(const float4*)(vnew + (size_t)(b * NKV + h) * DH + ql * 4);

    const int lim = live - 1;
    const int pw0 = p0 + wave * 64;
    const float* kb = kcache + (size_t)base * ROWF + h * DH + ql * 4;
    const float* vb = vcache + (size_t)base * ROWF + h * DH + ql * 4;

    // ---- Phase 1: scores (streams K). Branch-free: clamped addresses,
    // dead positions get -inf. Iterations fully independent.
#pragma unroll 8
    for (int i = 0; i < 32; ++i) {
        const int p  = pw0 + 2 * i + half;
        const int pc = min(p, lim);
        float4 kk = *(const float4*)(kb + ((size_t)pc << 10));
        if (pc == rep) kk = kn4;          // virtual scatter of the new token
#pragma unroll
        for (int g = 0; g < NG; ++g) {
            float d = kk.x * qv[g].x + kk.y * qv[g].y +
                      kk.z * qv[g].z + kk.w * qv[g].w;
            d = half_reduce_sum(d);
            const float s = (p <= lim) ? d * SCALE_LOG2E : -INFINITY;
            if (ql == 31) sc[g][p - p0] = s;   // lanes 31 & 63 write pair
        }
    }
    __syncthreads();

    // ---- Phase 2: block softmax for the whole chunk; wave g owns group g.
    {
        const int g = wave;
        const float s0 = sc[g][lane];
        const float s1 = sc[g][64 + lane];
        const float s2 = sc[g][128 + lane];
        const float s3 = sc[g][192 + lane];
        float m = fmaxf(fmaxf(s0, s1), fmaxf(s2, s3));
#pragma unroll
        for (int off = 1; off < 64; off <<= 1)
            m = fmaxf(m, __shfl_xor(m, off));
        const float e0 = exp2f(s0 - m);
        const float e1 = exp2f(s1 - m);
        const float e2 = exp2f(s2 - m);
        const float e3 = exp2f(s3 - m);
        float l = (e0 + e1) + (e2 + e3);
#pragma unroll
        for (int off = 1; off < 64; off <<= 1)
            l += __shfl_xor(l, off);
        sc[g][lane]       = e0;           // weights back to LDS
        sc[g][64 + lane]  = e1;
        sc[g][128 + lane] = e2;
        sc[g][192 + lane] = e3;
        if (lane == 0) {
            const size_t pidx = ((size_t)(b * NKV + h) * NG + g) * NCH + c;
            pml[pidx * 2]     = m;
            pml[pidx * 2 + 1] = l;
        }
    }
    __syncthreads();

    // ---- Phase 3: PV (streams V). Weights are broadcast LDS reads.
    float4 acc[NG];
#pragma unroll
    for (int g = 0; g < NG; ++g) acc[g] = make_float4(0.f, 0.f, 0.f, 0.f);

#pragma unroll 8
    for (int i = 0; i < 32; ++i) {
        const int p  = pw0 + 2 * i + half;
        const int pc = min(p, lim);
        float4 vv = *(const float4*)(vb + ((size_t)pc << 10));
        if (pc == rep) vv = vn4;
        const int pos = p - p0;
#pragma unroll
        for (int g = 0; g < NG; ++g) {
            const float w = sc[g][pos];   // 0 for dead positions
            acc[g].x += w * vv.x;
            acc[g].y += w * vv.y;
            acc[g].z += w * vv.z;
            acc[g].w += w * vv.w;
        }
    }

    // Combine the 8 half-wave partials (plain sums — shared m within block).
    const int hw = wave * 2 + half;
#pragma unroll
    for (int g = 0; g < NG; ++g)
        sacc[g][hw][ql] = acc[g];
    __syncthreads();

    if (half == 0) {                      // lanes 0..31 of wave g write group g
        const int g = wave;
        float4 o = make_float4(0.f, 0.f, 0.f, 0.f);
#pragma unroll
        for (int j = 0; j < 8; ++j) {
            const float4 a = sacc[g][j][ql];
            o.x += a.x; o.y += a.y; o.z += a.z; o.w += a.w;
        }
        const size_t pidx = ((size_t)(b * NKV + h) * NG + g) * NCH + c;
        *(float4*)(pacc + pidx * DH + ql * 4) = o;
    }
}

// Kernel 2: LSE-combine the <=8 chunk partials per (b, kv-head, group).
// No local arrays (avoids scratch); pml re-reads are L2-hot (64 KB total).
__global__ __launch_bounds__(256) void attn_combine_kernel(
    const int* __restrict__ live_counts,
    const float* __restrict__ pml,
    const float* __restrict__ pacc,
    float* __restrict__ out)
{
    const int h = blockIdx.x;
    const int b = blockIdx.y;
    const int g = (int)threadIdx.x >> 6;
    const int lane = (int)threadIdx.x & 63;   // 64 lanes x float2 = 128 dims

    const int live = live_counts[b];
    const int nc = (live + CHUNK - 1) / CHUNK;
    const size_t pbase = ((size_t)(b * NKV + h) * NG + g) * NCH;

    float M = -INFINITY;
    for (int cj = 0; cj < nc; ++cj)
        M = fmaxf(M, pml[(pbase + cj) * 2]);
    float L = 0.f;
    for (int cj = 0; cj < nc; ++cj)
        L += exp2f(pml[(pbase + cj) * 2] - M) * pml[(pbase + cj) * 2 + 1];
    float2 o = make_float2(0.f, 0.f);
    for (int cj = 0; cj < nc; ++cj) {
        const float w = exp2f(pml[(pbase + cj) * 2] - M);
        const float2 a = *(const float2*)(pacc + (pbase + cj) * DH + lane * 2);
        o.x += w * a.x;
        o.y += w * a.y;
    }
    const float inv = 1.f / L;
    o.x *= inv; o.y *= inv;
    *(float2*)(out + (size_t)(b * NH + h * NG + g) * DH + lane * 2) = o;
}

extern "C" void kernel_launch(void* const* d_in, const int* in_sizes, int n_in,
                              void* d_out, int out_size, void* d_ws, size_t ws_size,
                              hipStream_t stream) {
    const float* q    = (const float*)d_in[0];
    const float* knew = (const float*)d_in[1];
    const float* vnew = (const float*)d_in[2];
    const float* kc   = (const float*)d_in[3];
    const float* vc   = (const float*)d_in[4];
    const int* base   = (const int*)d_in[5];
    const int* live   = (const int*)d_in[6];
    const int* slot   = (const int*)d_in[7];
    float* out = (float*)d_out;

    // Workspace: pml = 2*(32*8*4*8) floats (64 KB), pacc = 8192*128 floats (4 MB)
    float* pml  = (float*)d_ws;
    float* pacc = pml + (size_t)2 * NB * NKV * NG * NCH;

    dim3 grid1(NCH, NKV, NB);   // 2048 blocks, ~1150 active
    attn_partial_kernel<<<grid1, 256, 0, stream>>>(q, knew, vnew, kc, vc,
                                                   base, live, slot, pml, pacc);
    dim3 grid2(NKV, NB);        // 256 blocks
    attn_combine_kernel<<<grid2, 256, 0, stream>>>(live, pml, pacc, out);
}